// Round 1
// 461.758 us; speedup vs baseline: 1.0563x; 1.0563x over previous
//
#include <hip/hip_runtime.h>

typedef short bf16x8 __attribute__((ext_vector_type(8)));
typedef float f32x4 __attribute__((ext_vector_type(4)));

namespace {
constexpr int kHW = 3136;
constexpr int kNPx = 32 * kHW;          // 100352 total pixels
constexpr int kPtiles = kNPx / 16;      // 6272
// xbi: [ptile][kb 0..7][l16*32k]  (K=256: 240 real + 16 zeros), 4096 shorts/pt
// y2i: [ptile][kb 0..3][l16*32k]  (K=128: 120 real + 8 garbage*zero-w), 2048/pt
// y1 : [px][120] plain bf16 (conv1 output, pre-dw)
constexpr size_t kXbiShorts = (size_t)kPtiles * 4096;  // 51.38 MB
constexpr size_t kY2iShorts = (size_t)kPtiles * 2048;  // 25.69 MB
}  // namespace

// interleaved bf16 weights (zero-padded outside each real K-range)
__device__ __align__(16) unsigned short g_w1i[3 * 4 * 48 * 32];  // [g][kb][j48][k32]
__device__ __align__(16) unsigned short g_wsci[8 * 480 * 32];    // [kb][co][k32], K=256
__device__ __align__(16) unsigned short g_w3i[2 * 480 * 32];     // [kb][co][k32]
__device__ __align__(16) float g_w2f[9 * 120];                   // [tap][c], scale2-folded

static __device__ __forceinline__ unsigned short f2b(float f) {
  unsigned u = __float_as_uint(f);
  u = (u + 0x7fffu + ((u >> 16) & 1u)) >> 16;  // RNE
  return (unsigned short)u;
}
static __device__ __forceinline__ float b2f(unsigned short u) {
  return __uint_as_float((unsigned)u << 16);
}
static __device__ __forceinline__ f32x4 mfma16(bf16x8 a, bf16x8 b, f32x4 c) {
  return __builtin_amdgcn_mfma_f32_16x16x32_bf16(a, b, c, 0, 0, 0);
}
static __device__ __forceinline__ bf16x8 ldg8(const unsigned short* p) {
  return *reinterpret_cast<const bf16x8*>(p);
}

// ---------------- weight prep: fp32 -> interleaved padded bf16 -------------
__global__ __launch_bounds__(256) void prep_weights(
    const float* __restrict__ w1, const float* __restrict__ wsc,
    const float* __restrict__ w3, const float* __restrict__ w2,
    const float* __restrict__ scale2) {
  const int idx = blockIdx.x * 256 + threadIdx.x;
  if (idx < 18432) {  // w1i
    const int g = idx / 6144, r = idx % 6144, kb = r / 1536;
    const int j = (r % 1536) / 32, k = r % 32;
    const int gk = g * 64 + kb * 32 + k;  // global cin-window position
    const int c = gk - g * 80;            // local cin within group
    unsigned short v = 0;
    if (j < 40 && c >= 0 && c < 80) v = f2b(w1[(g * 40 + j) * 80 + c]);
    g_w1i[idx] = v;
  } else if (idx < 18432 + 122880) {  // wsci
    const int i = idx - 18432;
    const int kb = i / 15360, co = (i % 15360) / 32, k = i % 32;
    const int c = kb * 32 + k;
    g_wsci[i] = (c < 240) ? f2b(wsc[co * 240 + c]) : (unsigned short)0;
  } else if (idx < 18432 + 122880 + 30720) {  // w3i
    const int i = idx - 141312;
    const int kb = i / 15360, co = (i % 15360) / 32, k = i % 32;
    const int cb = co / 160;
    const int s = cb * 32 + kb * 32 + k - cb * 40;  // local shuffled-ch index
    g_w3i[i] = (s >= 0 && s < 40) ? f2b(w3[co * 40 + s]) : (unsigned short)0;
  } else if (idx < 18432 + 122880 + 30720 + 1080) {  // w2f (scale2 folded)
    const int i = idx - 172032;
    const int tap = i / 120, c = i % 120;
    g_w2f[i] = w2[c * 9 + tap] * scale2[c];
  }
}

// ----- x [n][c][hw] f32 -> xbi interleaved bf16 (fully coalesced R/W) ------
__global__ __launch_bounds__(256) void transpose_interleave(
    const float* __restrict__ x, unsigned short* __restrict__ xbi) {
  // block: 64 px * 256 k. thread t: px_loc = t/4, part = t%4 (8 k's per kb)
  const int P0 = blockIdx.x * 64;
  const int px_loc = threadIdx.x >> 2, part = threadIdx.x & 3;
  const int P = P0 + px_loc;
  const int n = P / kHW, hw = P % kHW;
  const int pt = px_loc >> 4, l = px_loc & 15;
  unsigned short* dst =
      xbi + ((size_t)(P0 / 16) + pt) * 4096 + l * 32 + part * 8;
  const float* xp = x + ((size_t)n * 240) * kHW + hw;
#pragma unroll
  for (int kb = 0; kb < 8; ++kb) {
    unsigned short v[8];
#pragma unroll
    for (int j = 0; j < 8; ++j) {
      const int c = kb * 32 + part * 8 + j;
      v[j] = (c < 240) ? f2b(xp[(size_t)c * kHW]) : (unsigned short)0;
    }
    *reinterpret_cast<uint4*>(dst + kb * 512) =
        *reinterpret_cast<const uint4*>(v);
  }
}

// ---- conv1 (grouped 1x1) as clean full-image GEMM + BN1 + ReLU -> y1 ------
// No halo recompute: every pixel's conv1 is computed exactly once.
__global__ __launch_bounds__(256) void conv1_gemm(
    const unsigned short* __restrict__ xbi, const float* __restrict__ scale1,
    const float* __restrict__ shift1, unsigned short* __restrict__ y1) {
  const int lane = threadIdx.x & 63;
  const int wv = threadIdx.x >> 6;
  const int l15 = lane & 15, quad = lane >> 4;
  const size_t PT = (size_t)blockIdx.x * 8 + wv * 2;  // 2 ptiles per wave

#pragma unroll
  for (int g = 0; g < 3; ++g) {
    f32x4 acc[2][3];
#pragma unroll
    for (int mt = 0; mt < 2; ++mt)
#pragma unroll
      for (int nt = 0; nt < 3; ++nt) acc[mt][nt] = (f32x4){0.f, 0.f, 0.f, 0.f};
#pragma unroll
    for (int kb = 0; kb < 4; ++kb) {
      const int kbi = 2 * g + kb;  // K-window 64g..64g+128
      bf16x8 A[2];
#pragma unroll
      for (int mt = 0; mt < 2; ++mt)
        A[mt] = ldg8(xbi + (PT + mt) * 4096 + kbi * 512 + l15 * 32 + quad * 8);
#pragma unroll
      for (int nt = 0; nt < 3; ++nt) {
        const bf16x8 B = ldg8(g_w1i + (((g * 4 + kb) * 48) + nt * 16 + l15) * 32 +
                              quad * 8);
#pragma unroll
        for (int mt = 0; mt < 2; ++mt) acc[mt][nt] = mfma16(A[mt], B, acc[mt][nt]);
      }
    }
    // epilogue: BN1+ReLU -> y1[px][c] bf16
#pragma unroll
    for (int nt = 0; nt < 3; ++nt) {
      const int j = nt * 16 + l15;
      if (j < 40) {
        const int c = g * 40 + j;
        const float sc = scale1[c], sh = shift1[c];
#pragma unroll
        for (int mt = 0; mt < 2; ++mt) {
          const size_t pxb = (PT + mt) * 16 + quad * 4;
#pragma unroll
          for (int r = 0; r < 4; ++r) {
            float v = fmaf(acc[mt][nt][r], sc, sh);
            v = v > 0.f ? v : 0.f;
            y1[(pxb + r) * 120 + c] = f2b(v);
          }
        }
      }
    }
  }
}

// ---- depthwise 3x3 + BN2 (scale folded) + channel shuffle -> y2i ----------
// thread = (pixel, 8-channel group); y1 halo rows served by L1/L2.
__global__ __launch_bounds__(256) void dw_shuffle(
    const unsigned short* __restrict__ y1, const float* __restrict__ shift2,
    unsigned short* __restrict__ y2i) {
  const int idx = blockIdx.x * 256 + threadIdx.x;  // kNPx*15 threads total
  const int px = idx / 15, m = idx % 15;
  const int c0 = m * 8;
  const int n = px / kHW, hw = px % kHW;
  const int h = hw / 56, w = hw % 56;

  float acc[8];
  {
    const float4 s0 = *reinterpret_cast<const float4*>(shift2 + c0);
    const float4 s1 = *reinterpret_cast<const float4*>(shift2 + c0 + 4);
    acc[0] = s0.x; acc[1] = s0.y; acc[2] = s0.z; acc[3] = s0.w;
    acc[4] = s1.x; acc[5] = s1.y; acc[6] = s1.z; acc[7] = s1.w;
  }
  const unsigned short* yb = y1 + (size_t)n * kHW * 120 + c0;
#pragma unroll
  for (int dy = 0; dy < 3; ++dy) {
    const int hh = h + dy - 1;
    if (hh < 0 || hh >= 56) continue;
#pragma unroll
    for (int dx = 0; dx < 3; ++dx) {
      const int ww = w + dx - 1;
      if (ww < 0 || ww >= 56) continue;
      const bf16x8 v = ldg8(yb + (size_t)(hh * 56 + ww) * 120);
      const float* wp = g_w2f + (dy * 3 + dx) * 120 + c0;
      float wv_[8];
      *reinterpret_cast<float4*>(wv_) = *reinterpret_cast<const float4*>(wp);
      *reinterpret_cast<float4*>(wv_ + 4) =
          *reinterpret_cast<const float4*>(wp + 4);
#pragma unroll
      for (int j = 0; j < 8; ++j)
        acc[j] = fmaf(b2f((unsigned short)v[j]), wv_[j], acc[j]);
    }
  }
  // channel shuffle + scatter u16 write into interleaved y2i
  const size_t base = ((size_t)(px >> 4)) * 2048 + (px & 15) * 32;
#pragma unroll
  for (int j = 0; j < 8; ++j) {
    const int c = c0 + j;
    const int cn = (c % 40) * 3 + c / 40;  // channel shuffle
    y2i[base + (cn >> 5) * 512 + (cn & 31)] = f2b(acc[j]);
  }
}

// ---- fused conv3 + BN3 + ReLU + shortcut + BN_sc (folded accumulator) ------
__global__ __launch_bounds__(256, 3) void conv3_sc_gemm(
    const unsigned short* __restrict__ xbi,
    const unsigned short* __restrict__ y2i, const float* __restrict__ scale3,
    const float* __restrict__ shift3, const float* __restrict__ ssc,
    const float* __restrict__ bsc, float* __restrict__ out) {
  const int pxb = blockIdx.x % 784;  // 128-px blocks
  const int cb = blockIdx.x / 784;   // 160-co block == conv3 group
  const int P0 = pxb * 128;
  const int lane = threadIdx.x & 63;
  const int wv = threadIdx.x >> 6;
  const int mh = wv & 1, nh = wv >> 1;  // wave: 64 px x 80 co
  const int l15 = lane & 15, quad = lane >> 4;
  const int cbase = cb * 160 + nh * 80;

  f32x4 acc[4][5];
#pragma unroll
  for (int mt = 0; mt < 4; ++mt)
#pragma unroll
    for (int nt = 0; nt < 5; ++nt) acc[mt][nt] = (f32x4){0.f, 0.f, 0.f, 0.f};

  const size_t PT = (size_t)(P0 / 16) + mh * 4;

  // ---- phase 1: conv3 GEMM (K-window = 2 kb at offset cb) ----
#pragma unroll
  for (int kb = 0; kb < 2; ++kb) {
    const int kbi = cb + kb;
    bf16x8 A[4];
#pragma unroll
    for (int mt = 0; mt < 4; ++mt)
      A[mt] = ldg8(y2i + (PT + mt) * 2048 + kbi * 512 + l15 * 32 + quad * 8);
#pragma unroll
    for (int nt = 0; nt < 5; ++nt) {
      const bf16x8 B =
          ldg8(g_w3i + ((kb * 480) + cbase + nt * 16 + l15) * 32 + quad * 8);
#pragma unroll
      for (int mt = 0; mt < 4; ++mt) acc[mt][nt] = mfma16(A[mt], B, acc[mt][nt]);
    }
  }

  // ---- fold: acc = (relu(bn3) + shift_sc) / scale_sc ----
#pragma unroll
  for (int nt = 0; nt < 5; ++nt) {
    const int co = cbase + nt * 16 + l15;
    const float s3 = scale3[co], h3 = shift3[co];
    const float is = 1.0f / ssc[co], h_ = bsc[co];
#pragma unroll
    for (int mt = 0; mt < 4; ++mt)
#pragma unroll
      for (int r = 0; r < 4; ++r) {
        float v3 = fmaf(acc[mt][nt][r], s3, h3);
        v3 = v3 > 0.f ? v3 : 0.f;
        acc[mt][nt][r] = (v3 + h_) * is;
      }
  }

  // ---- phase 2: shortcut GEMM (K=256, 240 real) ----
  for (int kb = 0; kb < 8; ++kb) {
    bf16x8 A[4];
#pragma unroll
    for (int mt = 0; mt < 4; ++mt)
      A[mt] = ldg8(xbi + (PT + mt) * 4096 + kb * 512 + l15 * 32 + quad * 8);
#pragma unroll
    for (int nt = 0; nt < 5; ++nt) {
      const bf16x8 B =
          ldg8(g_wsci + ((kb * 480) + cbase + nt * 16 + l15) * 32 + quad * 8);
#pragma unroll
      for (int mt = 0; mt < 4; ++mt) acc[mt][nt] = mfma16(A[mt], B, acc[mt][nt]);
    }
  }

  // ---- store: out = scale_sc * acc ----
#pragma unroll
  for (int mt = 0; mt < 4; ++mt) {
    const int P = P0 + mh * 64 + mt * 16 + quad * 4;
    const int n = P / kHW, hw = P % kHW;
    float* ob = out + (size_t)n * 480 * kHW + hw;
#pragma unroll
    for (int nt = 0; nt < 5; ++nt) {
      const int co = cbase + nt * 16 + l15;
      const float s_ = ssc[co];
      float4 r;
      float* rp = reinterpret_cast<float*>(&r);
#pragma unroll
      for (int r4 = 0; r4 < 4; ++r4) rp[r4] = s_ * acc[mt][nt][r4];
      *reinterpret_cast<float4*>(ob + (size_t)co * kHW) = r;
    }
  }
}

extern "C" void kernel_launch(void* const* d_in, const int* in_sizes, int n_in,
                              void* d_out, int out_size, void* d_ws,
                              size_t ws_size, hipStream_t stream) {
  const float* x = (const float*)d_in[0];
  const float* w1 = (const float*)d_in[1];
  const float* scale1 = (const float*)d_in[2];
  const float* shift1 = (const float*)d_in[3];
  const float* w2 = (const float*)d_in[4];
  const float* scale2 = (const float*)d_in[5];
  const float* shift2 = (const float*)d_in[6];
  const float* w3 = (const float*)d_in[7];
  const float* scale3 = (const float*)d_in[8];
  const float* shift3 = (const float*)d_in[9];
  const float* wsc = (const float*)d_in[10];
  const float* ssc = (const float*)d_in[11];
  const float* bsc = (const float*)d_in[12];
  float* out = (float*)d_out;

  unsigned short* xbi = (unsigned short*)d_ws;
  unsigned short* y2i = xbi + kXbiShorts;
  unsigned short* y1 = y2i + kY2iShorts;  // total ws use: ~101 MB

  prep_weights<<<677, 256, 0, stream>>>(w1, wsc, w3, w2, scale2);
  transpose_interleave<<<kNPx / 64, 256, 0, stream>>>(x, xbi);
  conv1_gemm<<<kPtiles / 8, 256, 0, stream>>>(xbi, scale1, shift1, y1);
  dw_shuffle<<<kNPx * 15 / 256, 256, 0, stream>>>(y1, shift2, y2i);
  conv3_sc_gemm<<<784 * 3, 256, 0, stream>>>(xbi, y2i, scale3, shift3, ssc,
                                             bsc, out);
}

// Round 2
// 431.610 us; speedup vs baseline: 1.1301x; 1.0699x over previous
//
#include <hip/hip_runtime.h>

typedef short bf16x8 __attribute__((ext_vector_type(8)));
typedef float f32x4 __attribute__((ext_vector_type(4)));

namespace {
constexpr int kHW = 3136;
constexpr int kNPx = 32 * kHW;          // 100352 total pixels
constexpr int kPtiles = kNPx / 16;      // 6272
// xbi: [ptile][kb 0..7][l16*32k]  (K=256: 240 real + 16 zeros), 4096 shorts/pt
// y2i: [ptile][kb 0..3][l16*32k]  (K=128: 120 real + 8 zeros), 2048/pt
// y1 : [px][120] plain bf16 (conv1 output, pre-dw)
constexpr size_t kXbiShorts = (size_t)kPtiles * 4096;  // 51.38 MB
constexpr size_t kY2iShorts = (size_t)kPtiles * 2048;  // 25.69 MB
}  // namespace

// interleaved bf16 weights (zero-padded outside each real K-range)
__device__ __align__(16) unsigned short g_w1i[3 * 4 * 48 * 32];  // [g][kb][j48][k32]
__device__ __align__(16) unsigned short g_wsci[8 * 480 * 32];    // [kb][co][k32], K=256
__device__ __align__(16) unsigned short g_w3i[2 * 480 * 32];     // [kb][co][k32]
__device__ __align__(16) float g_w2f[9 * 120];                   // [tap][c], scale2-folded

static __device__ __forceinline__ unsigned short f2b(float f) {
  unsigned u = __float_as_uint(f);
  u = (u + 0x7fffu + ((u >> 16) & 1u)) >> 16;  // RNE
  return (unsigned short)u;
}
static __device__ __forceinline__ float b2f(unsigned short u) {
  return __uint_as_float((unsigned)u << 16);
}
static __device__ __forceinline__ f32x4 mfma16(bf16x8 a, bf16x8 b, f32x4 c) {
  return __builtin_amdgcn_mfma_f32_16x16x32_bf16(a, b, c, 0, 0, 0);
}
static __device__ __forceinline__ bf16x8 ldg8(const unsigned short* p) {
  return *reinterpret_cast<const bf16x8*>(p);
}

// ---------------- weight prep: fp32 -> interleaved padded bf16 -------------
__global__ __launch_bounds__(256) void prep_weights(
    const float* __restrict__ w1, const float* __restrict__ wsc,
    const float* __restrict__ w3, const float* __restrict__ w2,
    const float* __restrict__ scale2) {
  const int idx = blockIdx.x * 256 + threadIdx.x;
  if (idx < 18432) {  // w1i
    const int g = idx / 6144, r = idx % 6144, kb = r / 1536;
    const int j = (r % 1536) / 32, k = r % 32;
    const int gk = g * 64 + kb * 32 + k;  // global cin-window position
    const int c = gk - g * 80;            // local cin within group
    unsigned short v = 0;
    if (j < 40 && c >= 0 && c < 80) v = f2b(w1[(g * 40 + j) * 80 + c]);
    g_w1i[idx] = v;
  } else if (idx < 18432 + 122880) {  // wsci
    const int i = idx - 18432;
    const int kb = i / 15360, co = (i % 15360) / 32, k = i % 32;
    const int c = kb * 32 + k;
    g_wsci[i] = (c < 240) ? f2b(wsc[co * 240 + c]) : (unsigned short)0;
  } else if (idx < 18432 + 122880 + 30720) {  // w3i
    const int i = idx - 141312;
    const int kb = i / 15360, co = (i % 15360) / 32, k = i % 32;
    const int cb = co / 160;
    const int s = cb * 32 + kb * 32 + k - cb * 40;  // local shuffled-ch index
    g_w3i[i] = (s >= 0 && s < 40) ? f2b(w3[co * 40 + s]) : (unsigned short)0;
  } else if (idx < 18432 + 122880 + 30720 + 1080) {  // w2f (scale2 folded)
    const int i = idx - 172032;
    const int tap = i / 120, c = i % 120;
    g_w2f[i] = w2[c * 9 + tap] * scale2[c];
  }
}

// ----- x [n][c][hw] f32 -> xbi interleaved bf16 (fully coalesced R/W) ------
__global__ __launch_bounds__(256) void transpose_interleave(
    const float* __restrict__ x, unsigned short* __restrict__ xbi) {
  // block: 64 px * 256 k. thread t: px_loc = t/4, part = t%4 (8 k's per kb)
  const int P0 = blockIdx.x * 64;
  const int px_loc = threadIdx.x >> 2, part = threadIdx.x & 3;
  const int P = P0 + px_loc;
  const int n = P / kHW, hw = P % kHW;
  const int pt = px_loc >> 4, l = px_loc & 15;
  unsigned short* dst =
      xbi + ((size_t)(P0 / 16) + pt) * 4096 + l * 32 + part * 8;
  const float* xp = x + ((size_t)n * 240) * kHW + hw;
#pragma unroll
  for (int kb = 0; kb < 8; ++kb) {
    unsigned short v[8];
#pragma unroll
    for (int j = 0; j < 8; ++j) {
      const int c = kb * 32 + part * 8 + j;
      v[j] = (c < 240) ? f2b(xp[(size_t)c * kHW]) : (unsigned short)0;
    }
    *reinterpret_cast<uint4*>(dst + kb * 512) =
        *reinterpret_cast<const uint4*>(v);
  }
}

// ---- conv1 (grouped 1x1) as clean full-image GEMM + BN1 + ReLU -> y1 ------
__global__ __launch_bounds__(256) void conv1_gemm(
    const unsigned short* __restrict__ xbi, const float* __restrict__ scale1,
    const float* __restrict__ shift1, unsigned short* __restrict__ y1) {
  const int lane = threadIdx.x & 63;
  const int wv = threadIdx.x >> 6;
  const int l15 = lane & 15, quad = lane >> 4;
  const size_t PT = (size_t)blockIdx.x * 8 + wv * 2;  // 2 ptiles per wave

#pragma unroll
  for (int g = 0; g < 3; ++g) {
    f32x4 acc[2][3];
#pragma unroll
    for (int mt = 0; mt < 2; ++mt)
#pragma unroll
      for (int nt = 0; nt < 3; ++nt) acc[mt][nt] = (f32x4){0.f, 0.f, 0.f, 0.f};
#pragma unroll
    for (int kb = 0; kb < 4; ++kb) {
      const int kbi = 2 * g + kb;  // K-window 64g..64g+128
      bf16x8 A[2];
#pragma unroll
      for (int mt = 0; mt < 2; ++mt)
        A[mt] = ldg8(xbi + (PT + mt) * 4096 + kbi * 512 + l15 * 32 + quad * 8);
#pragma unroll
      for (int nt = 0; nt < 3; ++nt) {
        const bf16x8 B = ldg8(g_w1i + (((g * 4 + kb) * 48) + nt * 16 + l15) * 32 +
                              quad * 8);
#pragma unroll
        for (int mt = 0; mt < 2; ++mt) acc[mt][nt] = mfma16(A[mt], B, acc[mt][nt]);
      }
    }
    // epilogue: BN1+ReLU -> y1[px][c] bf16
#pragma unroll
    for (int nt = 0; nt < 3; ++nt) {
      const int j = nt * 16 + l15;
      if (j < 40) {
        const int c = g * 40 + j;
        const float sc = scale1[c], sh = shift1[c];
#pragma unroll
        for (int mt = 0; mt < 2; ++mt) {
          const size_t pxb = (PT + mt) * 16 + quad * 4;
#pragma unroll
          for (int r = 0; r < 4; ++r) {
            float v = fmaf(acc[mt][nt][r], sc, sh);
            v = v > 0.f ? v : 0.f;
            y1[(pxb + r) * 120 + c] = f2b(v);
          }
        }
      }
    }
  }
}

// ---- depthwise 3x3 + BN2 + channel shuffle -> y2i (coalesced via LDS) -----
// One block per ptile (16 px). Phase 1: 240 threads compute dw in original
// channel order (vector y1 reads) -> LDS. Phase 2: 256 threads emit the
// ptile's full 2048-short interleaved slice as coalesced 16B stores.
__global__ __launch_bounds__(256) void dw_shuffle(
    const unsigned short* __restrict__ y1, const float* __restrict__ shift2,
    unsigned short* __restrict__ y2i) {
  const int pt = blockIdx.x;
  const int t = threadIdx.x;
  __shared__ float lds_y2[16 * 121];  // stride 121: spreads banks

  if (t < 240) {
    const int px_l = t / 15, m = t % 15;
    const int c0 = m * 8;
    const int px = pt * 16 + px_l;
    const int n = px / kHW, hw = px % kHW;
    const int h = hw / 56, w = hw % 56;

    float acc[8];
    {
      const float4 s0 = *reinterpret_cast<const float4*>(shift2 + c0);
      const float4 s1 = *reinterpret_cast<const float4*>(shift2 + c0 + 4);
      acc[0] = s0.x; acc[1] = s0.y; acc[2] = s0.z; acc[3] = s0.w;
      acc[4] = s1.x; acc[5] = s1.y; acc[6] = s1.z; acc[7] = s1.w;
    }
    const unsigned short* yb = y1 + (size_t)n * kHW * 120 + c0;
#pragma unroll
    for (int dy = 0; dy < 3; ++dy) {
      const int hh = h + dy - 1;
      if (hh >= 0 && hh < 56) {
#pragma unroll
        for (int dx = 0; dx < 3; ++dx) {
          const int ww = w + dx - 1;
          if (ww >= 0 && ww < 56) {
            const bf16x8 v = ldg8(yb + (size_t)(hh * 56 + ww) * 120);
            const float* wp = g_w2f + (dy * 3 + dx) * 120 + c0;
            float wv_[8];
            *reinterpret_cast<float4*>(wv_) =
                *reinterpret_cast<const float4*>(wp);
            *reinterpret_cast<float4*>(wv_ + 4) =
                *reinterpret_cast<const float4*>(wp + 4);
#pragma unroll
            for (int j = 0; j < 8; ++j)
              acc[j] = fmaf(b2f((unsigned short)v[j]), wv_[j], acc[j]);
          }
        }
      }
    }
#pragma unroll
    for (int j = 0; j < 8; ++j) lds_y2[px_l * 121 + c0 + j] = acc[j];
  }
  __syncthreads();

  // phase 2: q = linear short index in the ptile's y2i slice
  const int q = t * 8;
  const int kb = q >> 9, r = q & 511, pxl = r >> 5, k0 = r & 31;
  unsigned short v[8];
#pragma unroll
  for (int j = 0; j < 8; ++j) {
    const int cn = kb * 32 + k0 + j;             // shuffled channel
    const int c = (cn % 3) * 40 + cn / 3;        // inverse shuffle
    v[j] = (cn < 120) ? f2b(lds_y2[pxl * 121 + c]) : (unsigned short)0;
  }
  *reinterpret_cast<uint4*>(y2i + (size_t)pt * 2048 + q) =
      *reinterpret_cast<const uint4*>(v);
}

// ---- fused conv3 + BN3 + ReLU + shortcut + BN_sc (folded accumulator) ------
// Logical block order: (pxb, cb) with cb fastest, so the 3 blocks sharing one
// xbi pixel-slice are adjacent; bijective XCD swizzle (2352 = 8*294) keeps
// them on the same XCD's L2 -> xbi fetched from HBM ~once instead of 3x.
__global__ __launch_bounds__(256, 3) void conv3_sc_gemm(
    const unsigned short* __restrict__ xbi,
    const unsigned short* __restrict__ y2i, const float* __restrict__ scale3,
    const float* __restrict__ shift3, const float* __restrict__ ssc,
    const float* __restrict__ bsc, float* __restrict__ out) {
  const int bid = blockIdx.x;                    // 2352 = 8 XCDs * 294
  const int l = (bid & 7) * 294 + (bid >> 3);    // bijective XCD swizzle
  const int pxb = l / 3;   // 128-px block
  const int cb = l % 3;    // 160-co block == conv3 group
  const int P0 = pxb * 128;
  const int lane = threadIdx.x & 63;
  const int wv = threadIdx.x >> 6;
  const int mh = wv & 1, nh = wv >> 1;  // wave: 64 px x 80 co
  const int l15 = lane & 15, quad = lane >> 4;
  const int cbase = cb * 160 + nh * 80;

  f32x4 acc[4][5];
#pragma unroll
  for (int mt = 0; mt < 4; ++mt)
#pragma unroll
    for (int nt = 0; nt < 5; ++nt) acc[mt][nt] = (f32x4){0.f, 0.f, 0.f, 0.f};

  const size_t PT = (size_t)(P0 / 16) + mh * 4;

  // ---- phase 1: conv3 GEMM (K-window = 2 kb at offset cb) ----
#pragma unroll
  for (int kb = 0; kb < 2; ++kb) {
    const int kbi = cb + kb;
    bf16x8 A[4];
#pragma unroll
    for (int mt = 0; mt < 4; ++mt)
      A[mt] = ldg8(y2i + (PT + mt) * 2048 + kbi * 512 + l15 * 32 + quad * 8);
#pragma unroll
    for (int nt = 0; nt < 5; ++nt) {
      const bf16x8 B =
          ldg8(g_w3i + ((kb * 480) + cbase + nt * 16 + l15) * 32 + quad * 8);
#pragma unroll
      for (int mt = 0; mt < 4; ++mt) acc[mt][nt] = mfma16(A[mt], B, acc[mt][nt]);
    }
  }

  // ---- fold: acc = (relu(bn3) + shift_sc) / scale_sc ----
#pragma unroll
  for (int nt = 0; nt < 5; ++nt) {
    const int co = cbase + nt * 16 + l15;
    const float s3 = scale3[co], h3 = shift3[co];
    const float is = 1.0f / ssc[co], h_ = bsc[co];
#pragma unroll
    for (int mt = 0; mt < 4; ++mt)
#pragma unroll
      for (int r = 0; r < 4; ++r) {
        float v3 = fmaf(acc[mt][nt][r], s3, h3);
        v3 = v3 > 0.f ? v3 : 0.f;
        acc[mt][nt][r] = (v3 + h_) * is;
      }
  }

  // ---- phase 2: shortcut GEMM (K=256, 240 real) ----
  for (int kb = 0; kb < 8; ++kb) {
    bf16x8 A[4];
#pragma unroll
    for (int mt = 0; mt < 4; ++mt)
      A[mt] = ldg8(xbi + (PT + mt) * 4096 + kb * 512 + l15 * 32 + quad * 8);
#pragma unroll
    for (int nt = 0; nt < 5; ++nt) {
      const bf16x8 B =
          ldg8(g_wsci + ((kb * 480) + cbase + nt * 16 + l15) * 32 + quad * 8);
#pragma unroll
      for (int mt = 0; mt < 4; ++mt) acc[mt][nt] = mfma16(A[mt], B, acc[mt][nt]);
    }
  }

  // ---- store: out = scale_sc * acc ----
#pragma unroll
  for (int mt = 0; mt < 4; ++mt) {
    const int P = P0 + mh * 64 + mt * 16 + quad * 4;
    const int n = P / kHW, hw = P % kHW;
    float* ob = out + (size_t)n * 480 * kHW + hw;
#pragma unroll
    for (int nt = 0; nt < 5; ++nt) {
      const int co = cbase + nt * 16 + l15;
      const float s_ = ssc[co];
      float4 r;
      float* rp = reinterpret_cast<float*>(&r);
#pragma unroll
      for (int r4 = 0; r4 < 4; ++r4) rp[r4] = s_ * acc[mt][nt][r4];
      *reinterpret_cast<float4*>(ob + (size_t)co * kHW) = r;
    }
  }
}

extern "C" void kernel_launch(void* const* d_in, const int* in_sizes, int n_in,
                              void* d_out, int out_size, void* d_ws,
                              size_t ws_size, hipStream_t stream) {
  const float* x = (const float*)d_in[0];
  const float* w1 = (const float*)d_in[1];
  const float* scale1 = (const float*)d_in[2];
  const float* shift1 = (const float*)d_in[3];
  const float* w2 = (const float*)d_in[4];
  const float* scale2 = (const float*)d_in[5];
  const float* shift2 = (const float*)d_in[6];
  const float* w3 = (const float*)d_in[7];
  const float* scale3 = (const float*)d_in[8];
  const float* shift3 = (const float*)d_in[9];
  const float* wsc = (const float*)d_in[10];
  const float* ssc = (const float*)d_in[11];
  const float* bsc = (const float*)d_in[12];
  float* out = (float*)d_out;

  unsigned short* xbi = (unsigned short*)d_ws;
  unsigned short* y2i = xbi + kXbiShorts;
  unsigned short* y1 = y2i + kY2iShorts;  // total ws use: ~101 MB

  prep_weights<<<677, 256, 0, stream>>>(w1, wsc, w3, w2, scale2);
  transpose_interleave<<<kNPx / 64, 256, 0, stream>>>(x, xbi);
  conv1_gemm<<<kPtiles / 8, 256, 0, stream>>>(xbi, scale1, shift1, y1);
  dw_shuffle<<<kPtiles, 256, 0, stream>>>(y1, shift2, y2i);
  conv3_sc_gemm<<<784 * 3, 256, 0, stream>>>(xbi, y2i, scale3, shift3, ssc,
                                             bsc, out);
}